// Round 16
// baseline (64.446 us; speedup 1.0000x reference)
//
#include <hip/hip_runtime.h>
#include <stdint.h>

typedef __attribute__((ext_vector_type(8))) short  short8;
typedef __attribute__((ext_vector_type(4))) float  f32x4;

static __device__ __forceinline__ uint32_t f2bf(float x) {
    union { float f; uint32_t u; } v; v.f = x;
    return (v.u + 0x7FFFu + ((v.u >> 16) & 1u)) >> 16;
}

// Fragment-order layout for a 16x32 bf16 MFMA operand tile:
//   frag[(tile*NKS + ks)*512 + lane*8 + e]  where lane = row16 + 16*kh, k = ks*32 + kh*8 + e

// ---------------- kernel 0: W1f prep only (consumed by ln_proj) — 32 blocks
__global__ __launch_bounds__(256) void prep_w1(
    const float* __restrict__ W1, uint16_t* __restrict__ W1f) {
    int idx = blockIdx.x * 256 + threadIdx.x;  // 0..8191
    int f = idx >> 7, c = idx & 127;
    int ftile = f >> 4, l16 = f & 15;
    int ks = c >> 5, kh = (c >> 3) & 3, e = c & 7;
    W1f[(size_t)(ftile * 4 + ks) * 512 + (l16 + 16 * kh) * 8 + e] =
        (uint16_t)f2bf(W1[f * 128 + c]);
}

// ---------------- kernel 1: LayerNorm + proj via MFMA -> At/Bt fragment order
// Blocks [0,2048): LN+proj. Blocks [2048,2560): W2f permute (consumed by NEXT kernel).
// At carries proj/128 (OPM scale folded in); Bt carries raw proj.
__global__ __launch_bounds__(256) void ln_proj(
    const float* __restrict__ mI, const float* __restrict__ lnw,
    const float* __restrict__ lnb, const uint16_t* __restrict__ W1f,
    const float* __restrict__ b1, const float* __restrict__ W2,
    uint16_t* __restrict__ At, uint16_t* __restrict__ Bt,
    uint16_t* __restrict__ W2f)
{
    const int t = threadIdx.x;
    const int bid = blockIdx.x;
    if (bid >= 2048) {                        // ---- W2f prep branch ----
        // coalesced fp32 reads; scattered 2B stores (non-blocking)
        int idx = (bid - 2048) * 256 + t;     // 0..131071, source-linear
        int f   = idx >> 10;
        int src = idx & 1023;                 // = c*32 + d
        int c = src >> 5, d = src & 31;
        int kd = d * 32 + c;
        int ftile = f >> 4, l16 = f & 15;
        int ks = kd >> 5, kh = (kd >> 3) & 3, e = kd & 7;
        W2f[(size_t)(ftile * 32 + ks) * 512 + (l16 + 16 * kh) * 8 + e] =
            (uint16_t)f2bf(W2[idx]);
        return;
    }

    __shared__ __align__(16) uint16_t mns[256 * 8];   // 4 KB, granule-swizzled
    const int i0 = (bid * 16) & 255;
    const int r  = bid >> 4;

    {
        int row = t >> 4, cb = t & 15;
        const float* rp = mI + ((size_t)bid * 16 + row) * 128 + cb * 8;
        float4 v0 = *(const float4*)(rp);
        float4 v1 = *(const float4*)(rp + 4);
        float s  = v0.x + v0.y + v0.z + v0.w + v1.x + v1.y + v1.z + v1.w;
        float ss = v0.x*v0.x + v0.y*v0.y + v0.z*v0.z + v0.w*v0.w
                 + v1.x*v1.x + v1.y*v1.y + v1.z*v1.z + v1.w*v1.w;
        #pragma unroll
        for (int off = 8; off > 0; off >>= 1) {
            s  += __shfl_xor(s, off);
            ss += __shfl_xor(ss, off);
        }
        float mean = s * (1.0f / 128.0f);
        float var  = ss * (1.0f / 128.0f) - mean * mean;
        float rstd = rsqrtf(var + 1e-5f);
        float4 wa = *(const float4*)(lnw + cb * 8);
        float4 wb = *(const float4*)(lnw + cb * 8 + 4);
        float4 ba = *(const float4*)(lnb + cb * 8);
        float4 bb = *(const float4*)(lnb + cb * 8 + 4);
        uint16_t y[8];
        y[0] = (uint16_t)f2bf((v0.x - mean) * rstd * wa.x + ba.x);
        y[1] = (uint16_t)f2bf((v0.y - mean) * rstd * wa.y + ba.y);
        y[2] = (uint16_t)f2bf((v0.z - mean) * rstd * wa.z + ba.z);
        y[3] = (uint16_t)f2bf((v0.w - mean) * rstd * wa.w + ba.w);
        y[4] = (uint16_t)f2bf((v1.x - mean) * rstd * wb.x + bb.x);
        y[5] = (uint16_t)f2bf((v1.y - mean) * rstd * wb.y + bb.y);
        y[6] = (uint16_t)f2bf((v1.z - mean) * rstd * wb.z + bb.z);
        y[7] = (uint16_t)f2bf((v1.w - mean) * rstd * wb.w + bb.w);
        int g = cb * 16 + (row ^ (cb & 7));           // swizzled granule
        *(uint2*)&mns[g * 8]     = *(uint2*)&y[0];
        *(uint2*)&mns[g * 8 + 4] = *(uint2*)&y[4];
    }
    __syncthreads();

    const int w = t >> 6, l = t & 63;
    const int l16 = l & 15, lh = l >> 4;
    f32x4 acc = (f32x4)(0.0f);
    #pragma unroll
    for (int ks = 0; ks < 4; ++ks) {
        int cb = ks * 4 + lh;
        int g  = cb * 16 + (l16 ^ (cb & 7));
        short8 a = *(const short8*)&mns[g * 8];
        short8 b = *(const short8*)(W1f + (size_t)(w * 4 + ks) * 512 + l * 8);
        acc = __builtin_amdgcn_mfma_f32_16x16x32_bf16(a, b, acc, 0, 0, 0);
    }
    float b1v = b1[w * 16 + l16];
    uint16_t* dst = (w < 2) ? At : Bt;
    const float scale = (w < 2) ? (1.0f / 128.0f) : 1.0f;   // fold OPM /128 into At
    const int cch = w & 1;
    const int base2 = (r >> 5) * 512 + (l16 + 16 * ((r >> 3) & 3)) * 8 + (r & 7);
    #pragma unroll
    for (int v = 0; v < 4; ++v) {
        int i = i0 + lh * 4 + v;
        int mtile = i * 2 + cch;
        dst[(size_t)mtile * 2048 + base2] = (uint16_t)f2bf((acc[v] + b1v) * scale);
    }
}

// ---------------- kernel 2: fused OPM GEMM + MFMA W2 epilogue (256x128 tile)
// 1-D grid 2048, XCD-bijective swizzle: lg = (id&7)*256 + id>>3; bx = lg&63, by = lg>>6.
// 512 thr, 8 waves. Main: C[256ic][128jd], wave (wm,wn) does 64x64.
// LDS:  Out in FRAGMENT ORDER [pt=2][ks=32][lane*8] bf16, ks-XOR swizzled (64 KB dynamic)
// Epi:  wave w = f-tile w, 2 p-tiles, 32 ks; W-prefetch depth 8, o-frag prefetch depth 4.
extern __shared__ uint16_t outl[];
__global__ __launch_bounds__(512, 4) void fused_opm(
    const uint16_t* __restrict__ At, const uint16_t* __restrict__ Bt,
    const uint16_t* __restrict__ W2f, const float* __restrict__ b2,
    float* __restrict__ z)
{
    const int t = threadIdx.x;
    const int w = t >> 6, l = t & 63;
    const int l16 = l & 15, lh = l >> 4;
    const int id = blockIdx.x;
    const int lg = ((id & 7) << 8) | (id >> 3);   // XCD-contiguous logical tile
    const int bx = lg & 63, by = lg >> 6;
    const int wm = w >> 1, wn = w & 1;

    // ---- main GEMM: contiguous 1KB/wave fragment loads ----
    f32x4 acc[4][4];
    #pragma unroll
    for (int a = 0; a < 4; ++a)
        #pragma unroll
        for (int b = 0; b < 4; ++b) acc[a][b] = (f32x4)(0.0f);

    const uint16_t* Abase = At + (size_t)(by * 16 + wm * 4) * 4 * 512 + l * 8;
    const uint16_t* Bbase = Bt + (size_t)(bx * 8 + wn * 4) * 4 * 512 + l * 8;
    __builtin_amdgcn_s_setprio(1);
    #pragma unroll
    for (int ks = 0; ks < 4; ++ks) {
        short8 af[4], bf[4];
        #pragma unroll
        for (int mt = 0; mt < 4; ++mt)
            af[mt] = *(const short8*)(Abase + (size_t)(mt * 4 + ks) * 512);
        #pragma unroll
        for (int nt = 0; nt < 4; ++nt)
            bf[nt] = *(const short8*)(Bbase + (size_t)(nt * 4 + ks) * 512);
        #pragma unroll
        for (int mt = 0; mt < 4; ++mt)
            #pragma unroll
            for (int nt = 0; nt < 4; ++nt)
                acc[mt][nt] = __builtin_amdgcn_mfma_f32_16x16x32_bf16(
                    af[mt], bf[nt], acc[mt][nt], 0, 0, 0);
    }
    __builtin_amdgcn_s_setprio(0);

    // ---- issue first 8 epilogue W-frag loads NOW (latency hides under C-write) ----
    const uint16_t* Wt = W2f + (size_t)w * 32 * 512 + l * 8;
    short8 wbuf[8];
    #pragma unroll
    for (int q = 0; q < 8; ++q)
        wbuf[q] = *(const short8*)(Wt + (size_t)q * 512);

    // ---- C (pre-scaled by 1/128 via At) -> bf16 -> Out LDS frag-order, ks-XOR swz ----
    // acc[mt][nt] reg v = C[ic = wm*64+mt*16+lh*4+v][jd = wn*64+nt*16+l16]
    // frag: ks = d; kh = (mt&1)*2+(lh>>1); e = (lh&1)*4 + v
    #pragma unroll
    for (int mt = 0; mt < 4; ++mt) {
        const int kh = (mt & 1) * 2 + (lh >> 1);
        const int e0 = (lh & 1) * 4;
        #pragma unroll
        for (int nt = 0; nt < 4; ++nt) {
            int p  = wm * 8 + (mt >> 1) * 4 + wn * 2 + (nt >> 1);
            int ks = (nt & 1) * 16 + l16;
            int ptw = p >> 4, l16t = p & 15;
            f32x4 v = acc[mt][nt];
            uint2 pk;
            pk.x = f2bf(v[0]) | (f2bf(v[1]) << 16);
            pk.y = f2bf(v[2]) | (f2bf(v[3]) << 16);
            uint32_t byte = (uint32_t)(ptw * 32 + ks) * 1024u
                          + (uint32_t)(l16t + 16 * kh) * 16u + (uint32_t)e0 * 2u;
            byte ^= (uint32_t)(ks & 7) << 4;
            *(uint2*)((char*)outl + byte) = pk;
        }
    }
    __syncthreads();

    // ---- epilogue: wave w = f-tile w; 2 p-tiles; 32 ks ----
    // W prefetch depth 8 (global), o-frag prefetch depth 4 (LDS).
    f32x4 zacc[2][2];
    #pragma unroll
    for (int a = 0; a < 2; ++a) { zacc[a][0] = (f32x4)(0.0f); zacc[a][1] = (f32x4)(0.0f); }

    const char* outb = (const char*)outl;
    #define OB0(ksv) ((((uint32_t)(ksv) * 1024u + (uint32_t)l * 16u)) ^ ((uint32_t)((ksv) & 7) << 4))
    #define OB1(ksv) ((((uint32_t)(32 + (ksv)) * 1024u + (uint32_t)l * 16u)) ^ ((uint32_t)((ksv) & 7) << 4))

    short8 ob0[4], ob1[4];
    #pragma unroll
    for (int q = 0; q < 4; ++q) {
        ob0[q] = *(const short8*)(outb + OB0(q));
        ob1[q] = *(const short8*)(outb + OB1(q));
    }
    __builtin_amdgcn_s_setprio(1);
    #pragma unroll
    for (int ks = 0; ks < 32; ++ks) {
        short8 cw = wbuf[ks & 7];
        if (ks < 24) wbuf[ks & 7] = *(const short8*)(Wt + (size_t)(ks + 8) * 512);
        short8 o0 = ob0[ks & 3], o1 = ob1[ks & 3];
        if (ks < 28) {
            ob0[ks & 3] = *(const short8*)(outb + OB0(ks + 4));
            ob1[ks & 3] = *(const short8*)(outb + OB1(ks + 4));
        }
        zacc[0][ks & 1] = __builtin_amdgcn_mfma_f32_16x16x32_bf16(cw, o0, zacc[0][ks & 1], 0, 0, 0);
        zacc[1][ks & 1] = __builtin_amdgcn_mfma_f32_16x16x32_bf16(cw, o1, zacc[1][ks & 1], 0, 0, 0);
    }
    __builtin_amdgcn_s_setprio(0);
    #undef OB0
    #undef OB1

    // ---- write z: lane p = pt*16+l16, rows f0 = w*16+lh*4 ----
    const int f0 = w * 16 + lh * 4;
    const float4 bv = *(const float4*)(b2 + f0);
    #pragma unroll
    for (int pt = 0; pt < 2; ++pt) {
        int p  = pt * 16 + l16;
        int zi = by * 8 + (p >> 2);
        int zj = bx * 4 + (p & 3);
        float* zrow = z + ((size_t)zi * 256 + zj) * 128;
        float4 zr;
        zr.x = zacc[pt][0][0] + zacc[pt][1][0] + bv.x;
        zr.y = zacc[pt][0][1] + zacc[pt][1][1] + bv.y;
        zr.z = zacc[pt][0][2] + zacc[pt][1][2] + bv.z;
        zr.w = zacc[pt][0][3] + zacc[pt][1][3] + bv.w;
        *(float4*)(zrow + f0) = zr;
    }
}

extern "C" void kernel_launch(void* const* d_in, const int* in_sizes, int n_in,
                              void* d_out, int out_size, void* d_ws, size_t ws_size,
                              hipStream_t stream) {
    const float* m_in = (const float*)d_in[0];
    const float* ln_w = (const float*)d_in[1];
    const float* ln_b = (const float*)d_in[2];
    const float* W1   = (const float*)d_in[3];
    const float* b1   = (const float*)d_in[4];
    const float* W2   = (const float*)d_in[5];
    const float* b2   = (const float*)d_in[6];
    float* z = (float*)d_out;

    uint16_t* At  = (uint16_t*)d_ws;                 // 2 MB
    uint16_t* Bt  = At + 8192 * 128;                 // 2 MB
    uint16_t* W2f = Bt + 8192 * 128;                 // 256 KB
    uint16_t* W1f = W2f + 128 * 1024;                // 16 KB

    prep_w1<<<32, 256, 0, stream>>>(W1, W1f);
    ln_proj<<<2560, 256, 0, stream>>>(m_in, ln_w, ln_b, W1f, b1, W2, At, Bt, W2f);
    fused_opm<<<2048, 512, 64 * 1024, stream>>>(At, Bt, W2f, b2, z);
}

// Round 19
// 63.811 us; speedup vs baseline: 1.0099x; 1.0099x over previous
//
#include <hip/hip_runtime.h>
#include <stdint.h>

typedef __attribute__((ext_vector_type(8))) short  short8;
typedef __attribute__((ext_vector_type(4))) float  f32x4;

static __device__ __forceinline__ uint32_t f2bf(float x) {
    union { float f; uint32_t u; } v; v.f = x;
    return (v.u + 0x7FFFu + ((v.u >> 16) & 1u)) >> 16;
}

// Fragment-order layout for a 16x32 bf16 MFMA operand tile:
//   frag[(tile*NKS + ks)*512 + lane*8 + e]  where lane = row16 + 16*kh, k = ks*32 + kh*8 + e

// ---------------- kernel 0: W1f prep only (consumed by ln_proj) — 32 blocks
__global__ __launch_bounds__(256) void prep_w1(
    const float* __restrict__ W1, uint16_t* __restrict__ W1f) {
    int idx = blockIdx.x * 256 + threadIdx.x;  // 0..8191
    int f = idx >> 7, c = idx & 127;
    int ftile = f >> 4, l16 = f & 15;
    int ks = c >> 5, kh = (c >> 3) & 3, e = c & 7;
    W1f[(size_t)(ftile * 4 + ks) * 512 + (l16 + 16 * kh) * 8 + e] =
        (uint16_t)f2bf(W1[f * 128 + c]);
}

// ---------------- kernel 1: LayerNorm + proj via MFMA -> At/Bt fragment order
// Blocks [0,2048): LN+proj. Blocks [2048,2560): W2f permute (consumed by NEXT kernel).
// At carries proj/128 (OPM scale folded in); Bt carries raw proj.
__global__ __launch_bounds__(256) void ln_proj(
    const float* __restrict__ mI, const float* __restrict__ lnw,
    const float* __restrict__ lnb, const uint16_t* __restrict__ W1f,
    const float* __restrict__ b1, const float* __restrict__ W2,
    uint16_t* __restrict__ At, uint16_t* __restrict__ Bt,
    uint16_t* __restrict__ W2f)
{
    const int t = threadIdx.x;
    const int bid = blockIdx.x;
    if (bid >= 2048) {                        // ---- W2f prep branch ----
        int idx = (bid - 2048) * 256 + t;     // 0..131071, source-linear
        int f   = idx >> 10;
        int src = idx & 1023;                 // = c*32 + d
        int c = src >> 5, d = src & 31;
        int kd = d * 32 + c;
        int ftile = f >> 4, l16 = f & 15;
        int ks = kd >> 5, kh = (kd >> 3) & 3, e = kd & 7;
        W2f[(size_t)(ftile * 32 + ks) * 512 + (l16 + 16 * kh) * 8 + e] =
            (uint16_t)f2bf(W2[idx]);
        return;
    }

    __shared__ __align__(16) uint16_t mns[256 * 8];   // 4 KB, granule-swizzled
    const int i0 = (bid * 16) & 255;
    const int r  = bid >> 4;

    {
        int row = t >> 4, cb = t & 15;
        const float* rp = mI + ((size_t)bid * 16 + row) * 128 + cb * 8;
        float4 v0 = *(const float4*)(rp);
        float4 v1 = *(const float4*)(rp + 4);
        float s  = v0.x + v0.y + v0.z + v0.w + v1.x + v1.y + v1.z + v1.w;
        float ss = v0.x*v0.x + v0.y*v0.y + v0.z*v0.z + v0.w*v0.w
                 + v1.x*v1.x + v1.y*v1.y + v1.z*v1.z + v1.w*v1.w;
        #pragma unroll
        for (int off = 8; off > 0; off >>= 1) {
            s  += __shfl_xor(s, off);
            ss += __shfl_xor(ss, off);
        }
        float mean = s * (1.0f / 128.0f);
        float var  = ss * (1.0f / 128.0f) - mean * mean;
        float rstd = rsqrtf(var + 1e-5f);
        float4 wa = *(const float4*)(lnw + cb * 8);
        float4 wb = *(const float4*)(lnw + cb * 8 + 4);
        float4 ba = *(const float4*)(lnb + cb * 8);
        float4 bb = *(const float4*)(lnb + cb * 8 + 4);
        uint16_t y[8];
        y[0] = (uint16_t)f2bf((v0.x - mean) * rstd * wa.x + ba.x);
        y[1] = (uint16_t)f2bf((v0.y - mean) * rstd * wa.y + ba.y);
        y[2] = (uint16_t)f2bf((v0.z - mean) * rstd * wa.z + ba.z);
        y[3] = (uint16_t)f2bf((v0.w - mean) * rstd * wa.w + ba.w);
        y[4] = (uint16_t)f2bf((v1.x - mean) * rstd * wb.x + bb.x);
        y[5] = (uint16_t)f2bf((v1.y - mean) * rstd * wb.y + bb.y);
        y[6] = (uint16_t)f2bf((v1.z - mean) * rstd * wb.z + bb.z);
        y[7] = (uint16_t)f2bf((v1.w - mean) * rstd * wb.w + bb.w);
        int g = cb * 16 + (row ^ (cb & 7));           // swizzled granule
        *(uint2*)&mns[g * 8]     = *(uint2*)&y[0];
        *(uint2*)&mns[g * 8 + 4] = *(uint2*)&y[4];
    }
    __syncthreads();

    const int w = t >> 6, l = t & 63;
    const int l16 = l & 15, lh = l >> 4;
    f32x4 acc = (f32x4)(0.0f);
    #pragma unroll
    for (int ks = 0; ks < 4; ++ks) {
        int cb = ks * 4 + lh;
        int g  = cb * 16 + (l16 ^ (cb & 7));
        short8 a = *(const short8*)&mns[g * 8];
        short8 b = *(const short8*)(W1f + (size_t)(w * 4 + ks) * 512 + l * 8);
        acc = __builtin_amdgcn_mfma_f32_16x16x32_bf16(a, b, acc, 0, 0, 0);
    }
    float b1v = b1[w * 16 + l16];
    uint16_t* dst = (w < 2) ? At : Bt;
    const float scale = (w < 2) ? (1.0f / 128.0f) : 1.0f;   // fold OPM /128 into At
    const int cch = w & 1;
    const int base2 = (r >> 5) * 512 + (l16 + 16 * ((r >> 3) & 3)) * 8 + (r & 7);
    #pragma unroll
    for (int v = 0; v < 4; ++v) {
        int i = i0 + lh * 4 + v;
        int mtile = i * 2 + cch;
        dst[(size_t)mtile * 2048 + base2] = (uint16_t)f2bf((acc[v] + b1v) * scale);
    }
}

// ---------------- kernel 2: fused OPM GEMM + MFMA W2 epilogue (256x128 tile)
// 1-D grid 2048, XCD-bijective swizzle: lg = (id&7)*256 + id>>3; bx = lg&63, by = lg>>6.
// 512 thr, 8 waves. Main: C[256ic][128jd], wave (wm,wn) does 64x64.
// B-panel (32 KB, fragment-order-contiguous) STAGED in LDS (read once from L2),
// then the SAME LDS region is reused for Out after a barrier (B dead by then).
// LDS:  Out in FRAGMENT ORDER [pt=2][ks=32][lane*8] bf16, ks-XOR swizzled (64 KB dynamic)
// Epi:  wave w = f-tile w, 2 p-tiles, 32 ks; W-prefetch depth 8, o-frag prefetch depth 2.
extern __shared__ uint16_t outl[];
__global__ __launch_bounds__(512, 4) void fused_opm(
    const uint16_t* __restrict__ At, const uint16_t* __restrict__ Bt,
    const uint16_t* __restrict__ W2f, const float* __restrict__ b2,
    float* __restrict__ z)
{
    const int t = threadIdx.x;
    const int w = t >> 6, l = t & 63;
    const int l16 = l & 15, lh = l >> 4;
    const int id = blockIdx.x;
    const int lg = ((id & 7) << 8) | (id >> 3);   // XCD-contiguous logical tile
    const int bx = lg & 63, by = lg >> 6;
    const int wm = w >> 1, wn = w & 1;

    // ---- stage B panel (32 KB, contiguous) into LDS[0,32K): linear copy ----
    {
        const uint16_t* Bpanel = Bt + (size_t)bx * 16384;
        #pragma unroll
        for (int q = 0; q < 4; ++q) {
            int idx = q * 512 + t;                       // 0..2047 sixteen-byte units
            short8 v = *(const short8*)(Bpanel + (size_t)idx * 8);
            *(short8*)((char*)outl + (size_t)idx * 16) = v;
        }
    }
    __syncthreads();

    // ---- main GEMM: A-frags from global (1KB/wave), B-frags from LDS ----
    f32x4 acc[4][4];
    #pragma unroll
    for (int a = 0; a < 4; ++a)
        #pragma unroll
        for (int b = 0; b < 4; ++b) acc[a][b] = (f32x4)(0.0f);

    const uint16_t* Abase = At + (size_t)(by * 16 + wm * 4) * 4 * 512 + l * 8;
    const char* Blds = (const char*)outl + (size_t)wn * 16384 + (size_t)l * 16;
    __builtin_amdgcn_s_setprio(1);
    #pragma unroll
    for (int ks = 0; ks < 4; ++ks) {
        short8 af[4], bf[4];
        #pragma unroll
        for (int mt = 0; mt < 4; ++mt)
            af[mt] = *(const short8*)(Abase + (size_t)(mt * 4 + ks) * 512);
        #pragma unroll
        for (int nt = 0; nt < 4; ++nt)
            bf[nt] = *(const short8*)(Blds + (size_t)(nt * 4 + ks) * 1024);
        #pragma unroll
        for (int mt = 0; mt < 4; ++mt)
            #pragma unroll
            for (int nt = 0; nt < 4; ++nt)
                acc[mt][nt] = __builtin_amdgcn_mfma_f32_16x16x32_bf16(
                    af[mt], bf[nt], acc[mt][nt], 0, 0, 0);
    }
    __builtin_amdgcn_s_setprio(0);
    __syncthreads();    // all B reads done before Out overwrites the region

    // ---- issue first 8 epilogue W-frag loads NOW (latency hides under C-write) ----
    const uint16_t* Wt = W2f + (size_t)w * 32 * 512 + l * 8;
    short8 wbuf[8];
    #pragma unroll
    for (int q = 0; q < 8; ++q)
        wbuf[q] = *(const short8*)(Wt + (size_t)q * 512);

    // ---- C (pre-scaled by 1/128 via At) -> bf16 -> Out LDS frag-order, ks-XOR swz ----
    // acc[mt][nt] reg v = C[ic = wm*64+mt*16+lh*4+v][jd = wn*64+nt*16+l16]
    // frag: ks = d; kh = (mt&1)*2+(lh>>1); e = (lh&1)*4 + v
    #pragma unroll
    for (int mt = 0; mt < 4; ++mt) {
        const int kh = (mt & 1) * 2 + (lh >> 1);
        const int e0 = (lh & 1) * 4;
        #pragma unroll
        for (int nt = 0; nt < 4; ++nt) {
            int p  = wm * 8 + (mt >> 1) * 4 + wn * 2 + (nt >> 1);
            int ks = (nt & 1) * 16 + l16;
            int ptw = p >> 4, l16t = p & 15;
            f32x4 v = acc[mt][nt];
            uint2 pk;
            pk.x = f2bf(v[0]) | (f2bf(v[1]) << 16);
            pk.y = f2bf(v[2]) | (f2bf(v[3]) << 16);
            uint32_t byte = (uint32_t)(ptw * 32 + ks) * 1024u
                          + (uint32_t)(l16t + 16 * kh) * 16u + (uint32_t)e0 * 2u;
            byte ^= (uint32_t)(ks & 7) << 4;
            *(uint2*)((char*)outl + byte) = pk;
        }
    }
    __syncthreads();

    // ---- epilogue: wave w = f-tile w; 2 p-tiles; 32 ks ----
    // W prefetch depth 8 (global), o-frag prefetch depth 2 (LDS).
    f32x4 zacc[2][2];
    #pragma unroll
    for (int a = 0; a < 2; ++a) { zacc[a][0] = (f32x4)(0.0f); zacc[a][1] = (f32x4)(0.0f); }

    const char* outb = (const char*)outl;
    #define OB0(ksv) ((((uint32_t)(ksv) * 1024u + (uint32_t)l * 16u)) ^ ((uint32_t)((ksv) & 7) << 4))
    #define OB1(ksv) ((((uint32_t)(32 + (ksv)) * 1024u + (uint32_t)l * 16u)) ^ ((uint32_t)((ksv) & 7) << 4))

    short8 o0c = *(const short8*)(outb + OB0(0));
    short8 o1c = *(const short8*)(outb + OB1(0));
    __builtin_amdgcn_s_setprio(1);
    #pragma unroll
    for (int ks = 0; ks < 32; ++ks) {
        short8 cw = wbuf[ks & 7];
        if (ks < 24) wbuf[ks & 7] = *(const short8*)(Wt + (size_t)(ks + 8) * 512);
        short8 o0 = o0c, o1 = o1c;
        if (ks < 31) {
            o0c = *(const short8*)(outb + OB0(ks + 1));
            o1c = *(const short8*)(outb + OB1(ks + 1));
        }
        zacc[0][ks & 1] = __builtin_amdgcn_mfma_f32_16x16x32_bf16(cw, o0, zacc[0][ks & 1], 0, 0, 0);
        zacc[1][ks & 1] = __builtin_amdgcn_mfma_f32_16x16x32_bf16(cw, o1, zacc[1][ks & 1], 0, 0, 0);
    }
    __builtin_amdgcn_s_setprio(0);
    #undef OB0
    #undef OB1

    // ---- write z: lane p = pt*16+l16, rows f0 = w*16+lh*4 ----
    const int f0 = w * 16 + lh * 4;
    const float4 bv = *(const float4*)(b2 + f0);
    #pragma unroll
    for (int pt = 0; pt < 2; ++pt) {
        int p  = pt * 16 + l16;
        int zi = by * 8 + (p >> 2);
        int zj = bx * 4 + (p & 3);
        float* zrow = z + ((size_t)zi * 256 + zj) * 128;
        float4 zr;
        zr.x = zacc[pt][0][0] + zacc[pt][1][0] + bv.x;
        zr.y = zacc[pt][0][1] + zacc[pt][1][1] + bv.y;
        zr.z = zacc[pt][0][2] + zacc[pt][1][2] + bv.z;
        zr.w = zacc[pt][0][3] + zacc[pt][1][3] + bv.w;
        *(float4*)(zrow + f0) = zr;
    }
}

extern "C" void kernel_launch(void* const* d_in, const int* in_sizes, int n_in,
                              void* d_out, int out_size, void* d_ws, size_t ws_size,
                              hipStream_t stream) {
    const float* m_in = (const float*)d_in[0];
    const float* ln_w = (const float*)d_in[1];
    const float* ln_b = (const float*)d_in[2];
    const float* W1   = (const float*)d_in[3];
    const float* b1   = (const float*)d_in[4];
    const float* W2   = (const float*)d_in[5];
    const float* b2   = (const float*)d_in[6];
    float* z = (float*)d_out;

    uint16_t* At  = (uint16_t*)d_ws;                 // 2 MB
    uint16_t* Bt  = At + 8192 * 128;                 // 2 MB
    uint16_t* W2f = Bt + 8192 * 128;                 // 256 KB
    uint16_t* W1f = W2f + 128 * 1024;                // 16 KB

    prep_w1<<<32, 256, 0, stream>>>(W1, W1f);
    ln_proj<<<2560, 256, 0, stream>>>(m_in, ln_w, ln_b, W1f, b1, W2, At, Bt, W2f);
    fused_opm<<<2048, 512, 64 * 1024, stream>>>(At, Bt, W2f, b2, z);
}

// Round 20
// 63.772 us; speedup vs baseline: 1.0106x; 1.0006x over previous
//
#include <hip/hip_runtime.h>
#include <stdint.h>

typedef __attribute__((ext_vector_type(8))) short  short8;
typedef __attribute__((ext_vector_type(4))) float  f32x4;

static __device__ __forceinline__ uint32_t f2bf(float x) {
    union { float f; uint32_t u; } v; v.f = x;
    return (v.u + 0x7FFFu + ((v.u >> 16) & 1u)) >> 16;
}

// Fragment-order layout for a 16x32 bf16 MFMA operand tile:
//   frag[(tile*NKS + ks)*512 + lane*8 + e]  where lane = row16 + 16*kh, k = ks*32 + kh*8 + e

// ---------------- kernel 0: W1f prep only (consumed by ln_proj) — 32 blocks
__global__ __launch_bounds__(256) void prep_w1(
    const float* __restrict__ W1, uint16_t* __restrict__ W1f) {
    int idx = blockIdx.x * 256 + threadIdx.x;  // 0..8191
    int f = idx >> 7, c = idx & 127;
    int ftile = f >> 4, l16 = f & 15;
    int ks = c >> 5, kh = (c >> 3) & 3, e = c & 7;
    W1f[(size_t)(ftile * 4 + ks) * 512 + (l16 + 16 * kh) * 8 + e] =
        (uint16_t)f2bf(W1[f * 128 + c]);
}

// ---------------- kernel 1: LayerNorm + proj via MFMA -> At/Bt fragment order
// Blocks [0,2048): LN+proj. Blocks [2048,2560): W2f permute (consumed by NEXT kernel).
// At carries proj/128 (OPM scale folded in); Bt carries raw proj.
__global__ __launch_bounds__(256) void ln_proj(
    const float* __restrict__ mI, const float* __restrict__ lnw,
    const float* __restrict__ lnb, const uint16_t* __restrict__ W1f,
    const float* __restrict__ b1, const float* __restrict__ W2,
    uint16_t* __restrict__ At, uint16_t* __restrict__ Bt,
    uint16_t* __restrict__ W2f)
{
    const int t = threadIdx.x;
    const int bid = blockIdx.x;
    if (bid >= 2048) {                        // ---- W2f prep branch ----
        int idx = (bid - 2048) * 256 + t;     // 0..131071, source-linear
        int f   = idx >> 10;
        int src = idx & 1023;                 // = c*32 + d
        int c = src >> 5, d = src & 31;
        int kd = d * 32 + c;
        int ftile = f >> 4, l16 = f & 15;
        int ks = kd >> 5, kh = (kd >> 3) & 3, e = kd & 7;
        W2f[(size_t)(ftile * 32 + ks) * 512 + (l16 + 16 * kh) * 8 + e] =
            (uint16_t)f2bf(W2[idx]);
        return;
    }

    __shared__ __align__(16) uint16_t mns[256 * 8];   // 4 KB, granule-swizzled
    const int i0 = (bid * 16) & 255;
    const int r  = bid >> 4;

    {
        int row = t >> 4, cb = t & 15;
        const float* rp = mI + ((size_t)bid * 16 + row) * 128 + cb * 8;
        float4 v0 = *(const float4*)(rp);
        float4 v1 = *(const float4*)(rp + 4);
        float s  = v0.x + v0.y + v0.z + v0.w + v1.x + v1.y + v1.z + v1.w;
        float ss = v0.x*v0.x + v0.y*v0.y + v0.z*v0.z + v0.w*v0.w
                 + v1.x*v1.x + v1.y*v1.y + v1.z*v1.z + v1.w*v1.w;
        #pragma unroll
        for (int off = 8; off > 0; off >>= 1) {
            s  += __shfl_xor(s, off);
            ss += __shfl_xor(ss, off);
        }
        float mean = s * (1.0f / 128.0f);
        float var  = ss * (1.0f / 128.0f) - mean * mean;
        float rstd = rsqrtf(var + 1e-5f);
        float4 wa = *(const float4*)(lnw + cb * 8);
        float4 wb = *(const float4*)(lnw + cb * 8 + 4);
        float4 ba = *(const float4*)(lnb + cb * 8);
        float4 bb = *(const float4*)(lnb + cb * 8 + 4);
        uint16_t y[8];
        y[0] = (uint16_t)f2bf((v0.x - mean) * rstd * wa.x + ba.x);
        y[1] = (uint16_t)f2bf((v0.y - mean) * rstd * wa.y + ba.y);
        y[2] = (uint16_t)f2bf((v0.z - mean) * rstd * wa.z + ba.z);
        y[3] = (uint16_t)f2bf((v0.w - mean) * rstd * wa.w + ba.w);
        y[4] = (uint16_t)f2bf((v1.x - mean) * rstd * wb.x + bb.x);
        y[5] = (uint16_t)f2bf((v1.y - mean) * rstd * wb.y + bb.y);
        y[6] = (uint16_t)f2bf((v1.z - mean) * rstd * wb.z + bb.z);
        y[7] = (uint16_t)f2bf((v1.w - mean) * rstd * wb.w + bb.w);
        int g = cb * 16 + (row ^ (cb & 7));           // swizzled granule
        *(uint2*)&mns[g * 8]     = *(uint2*)&y[0];
        *(uint2*)&mns[g * 8 + 4] = *(uint2*)&y[4];
    }
    __syncthreads();

    const int w = t >> 6, l = t & 63;
    const int l16 = l & 15, lh = l >> 4;
    f32x4 acc = (f32x4)(0.0f);
    #pragma unroll
    for (int ks = 0; ks < 4; ++ks) {
        int cb = ks * 4 + lh;
        int g  = cb * 16 + (l16 ^ (cb & 7));
        short8 a = *(const short8*)&mns[g * 8];
        short8 b = *(const short8*)(W1f + (size_t)(w * 4 + ks) * 512 + l * 8);
        acc = __builtin_amdgcn_mfma_f32_16x16x32_bf16(a, b, acc, 0, 0, 0);
    }
    float b1v = b1[w * 16 + l16];
    uint16_t* dst = (w < 2) ? At : Bt;
    const float scale = (w < 2) ? (1.0f / 128.0f) : 1.0f;   // fold OPM /128 into At
    const int cch = w & 1;
    const int base2 = (r >> 5) * 512 + (l16 + 16 * ((r >> 3) & 3)) * 8 + (r & 7);
    #pragma unroll
    for (int v = 0; v < 4; ++v) {
        int i = i0 + lh * 4 + v;
        int mtile = i * 2 + cch;
        dst[(size_t)mtile * 2048 + base2] = (uint16_t)f2bf((acc[v] + b1v) * scale);
    }
}

// ---------------- kernel 2: fused OPM GEMM + MFMA W2 epilogue (256x128 tile)
// 1-D grid 2048, XCD-bijective swizzle: lg = (id&7)*256 + id>>3; bx = lg&63, by = lg>>6.
// 512 thr, 8 waves. Main: C[256ic][128jd], wave (wm,wn) does 64x64.
// B-panel (32 KB) staged via async global_load_lds width-16 (no VGPR round trip);
// ks=0 A-frags preloaded pre-barrier (latency overlaps B-DMA). Out LDS region
// reuses the B region after a barrier. Out in FRAGMENT ORDER, ks-XOR swizzled.
// Epi: wave w = f-tile w, 2 p-tiles, 32 ks; W-prefetch depth 8, o-frag depth 2.
extern __shared__ uint16_t outl[];
__global__ __launch_bounds__(512, 4) void fused_opm(
    const uint16_t* __restrict__ At, const uint16_t* __restrict__ Bt,
    const uint16_t* __restrict__ W2f, const float* __restrict__ b2,
    float* __restrict__ z)
{
    const int t = threadIdx.x;
    const int w = t >> 6, l = t & 63;
    const int l16 = l & 15, lh = l >> 4;
    const int id = blockIdx.x;
    const int lg = ((id & 7) << 8) | (id >> 3);   // XCD-contiguous logical tile
    const int bx = lg & 63, by = lg >> 6;
    const int wm = w >> 1, wn = w & 1;

    // ---- stage B panel (32 KB) into LDS[0,32K) via global_load_lds (async) ----
    // dest per q: wave-uniform base (q*512 + w*64)*16B, lane adds l*16B — matches
    // per-lane source (q*512 + t)*16B exactly (linear layout requirement, m104).
    {
        const uint16_t* Bp = Bt + (size_t)bx * 16384 + (size_t)t * 8;
        uint16_t* dstbase = outl + (size_t)(t & 448) * 8;   // (w*64)*8 elems
        #pragma unroll
        for (int q = 0; q < 4; ++q) {
            __builtin_amdgcn_global_load_lds(
                (const __attribute__((address_space(1))) void*)(Bp + (size_t)q * 4096),
                (__attribute__((address_space(3))) void*)(dstbase + (size_t)q * 4096),
                16, 0, 0);
        }
    }

    // ---- preload ks=0 A-frags NOW (L2 latency overlaps the B-stage DMA) ----
    const uint16_t* Abase = At + (size_t)(by * 16 + wm * 4) * 4 * 512 + l * 8;
    short8 af0[4];
    #pragma unroll
    for (int mt = 0; mt < 4; ++mt)
        af0[mt] = *(const short8*)(Abase + (size_t)(mt * 4) * 512);

    __syncthreads();

    // ---- main GEMM: A-frags from global (1KB/wave), B-frags from LDS ----
    f32x4 acc[4][4];
    #pragma unroll
    for (int a = 0; a < 4; ++a)
        #pragma unroll
        for (int b = 0; b < 4; ++b) acc[a][b] = (f32x4)(0.0f);

    const char* Blds = (const char*)outl + (size_t)wn * 16384 + (size_t)l * 16;
    __builtin_amdgcn_s_setprio(1);
    #pragma unroll
    for (int ks = 0; ks < 4; ++ks) {
        short8 af[4], bf[4];
        #pragma unroll
        for (int mt = 0; mt < 4; ++mt)
            af[mt] = (ks == 0) ? af0[mt]
                   : *(const short8*)(Abase + (size_t)(mt * 4 + ks) * 512);
        #pragma unroll
        for (int nt = 0; nt < 4; ++nt)
            bf[nt] = *(const short8*)(Blds + (size_t)(nt * 4 + ks) * 1024);
        #pragma unroll
        for (int mt = 0; mt < 4; ++mt)
            #pragma unroll
            for (int nt = 0; nt < 4; ++nt)
                acc[mt][nt] = __builtin_amdgcn_mfma_f32_16x16x32_bf16(
                    af[mt], bf[nt], acc[mt][nt], 0, 0, 0);
    }
    __builtin_amdgcn_s_setprio(0);
    __syncthreads();    // all B reads done before Out overwrites the region

    // ---- issue first 8 epilogue W-frag loads NOW (latency hides under C-write) ----
    const uint16_t* Wt = W2f + (size_t)w * 32 * 512 + l * 8;
    short8 wbuf[8];
    #pragma unroll
    for (int q = 0; q < 8; ++q)
        wbuf[q] = *(const short8*)(Wt + (size_t)q * 512);

    // ---- C (pre-scaled by 1/128 via At) -> bf16 -> Out LDS frag-order, ks-XOR swz ----
    // acc[mt][nt] reg v = C[ic = wm*64+mt*16+lh*4+v][jd = wn*64+nt*16+l16]
    // frag: ks = d; kh = (mt&1)*2+(lh>>1); e = (lh&1)*4 + v
    #pragma unroll
    for (int mt = 0; mt < 4; ++mt) {
        const int kh = (mt & 1) * 2 + (lh >> 1);
        const int e0 = (lh & 1) * 4;
        #pragma unroll
        for (int nt = 0; nt < 4; ++nt) {
            int p  = wm * 8 + (mt >> 1) * 4 + wn * 2 + (nt >> 1);
            int ks = (nt & 1) * 16 + l16;
            int ptw = p >> 4, l16t = p & 15;
            f32x4 v = acc[mt][nt];
            uint2 pk;
            pk.x = f2bf(v[0]) | (f2bf(v[1]) << 16);
            pk.y = f2bf(v[2]) | (f2bf(v[3]) << 16);
            uint32_t byte = (uint32_t)(ptw * 32 + ks) * 1024u
                          + (uint32_t)(l16t + 16 * kh) * 16u + (uint32_t)e0 * 2u;
            byte ^= (uint32_t)(ks & 7) << 4;
            *(uint2*)((char*)outl + byte) = pk;
        }
    }
    __syncthreads();

    // ---- epilogue: wave w = f-tile w; 2 p-tiles; 32 ks ----
    // W prefetch depth 8 (global), o-frag prefetch depth 2 (LDS).
    f32x4 zacc[2][2];
    #pragma unroll
    for (int a = 0; a < 2; ++a) { zacc[a][0] = (f32x4)(0.0f); zacc[a][1] = (f32x4)(0.0f); }

    const char* outb = (const char*)outl;
    #define OB0(ksv) ((((uint32_t)(ksv) * 1024u + (uint32_t)l * 16u)) ^ ((uint32_t)((ksv) & 7) << 4))
    #define OB1(ksv) ((((uint32_t)(32 + (ksv)) * 1024u + (uint32_t)l * 16u)) ^ ((uint32_t)((ksv) & 7) << 4))

    short8 o0c = *(const short8*)(outb + OB0(0));
    short8 o1c = *(const short8*)(outb + OB1(0));
    __builtin_amdgcn_s_setprio(1);
    #pragma unroll
    for (int ks = 0; ks < 32; ++ks) {
        short8 cw = wbuf[ks & 7];
        if (ks < 24) wbuf[ks & 7] = *(const short8*)(Wt + (size_t)(ks + 8) * 512);
        short8 o0 = o0c, o1 = o1c;
        if (ks < 31) {
            o0c = *(const short8*)(outb + OB0(ks + 1));
            o1c = *(const short8*)(outb + OB1(ks + 1));
        }
        zacc[0][ks & 1] = __builtin_amdgcn_mfma_f32_16x16x32_bf16(cw, o0, zacc[0][ks & 1], 0, 0, 0);
        zacc[1][ks & 1] = __builtin_amdgcn_mfma_f32_16x16x32_bf16(cw, o1, zacc[1][ks & 1], 0, 0, 0);
    }
    __builtin_amdgcn_s_setprio(0);
    #undef OB0
    #undef OB1

    // ---- write z: lane p = pt*16+l16, rows f0 = w*16+lh*4 ----
    const int f0 = w * 16 + lh * 4;
    const float4 bv = *(const float4*)(b2 + f0);
    #pragma unroll
    for (int pt = 0; pt < 2; ++pt) {
        int p  = pt * 16 + l16;
        int zi = by * 8 + (p >> 2);
        int zj = bx * 4 + (p & 3);
        float* zrow = z + ((size_t)zi * 256 + zj) * 128;
        float4 zr;
        zr.x = zacc[pt][0][0] + zacc[pt][1][0] + bv.x;
        zr.y = zacc[pt][0][1] + zacc[pt][1][1] + bv.y;
        zr.z = zacc[pt][0][2] + zacc[pt][1][2] + bv.z;
        zr.w = zacc[pt][0][3] + zacc[pt][1][3] + bv.w;
        *(float4*)(zrow + f0) = zr;
    }
}

extern "C" void kernel_launch(void* const* d_in, const int* in_sizes, int n_in,
                              void* d_out, int out_size, void* d_ws, size_t ws_size,
                              hipStream_t stream) {
    const float* m_in = (const float*)d_in[0];
    const float* ln_w = (const float*)d_in[1];
    const float* ln_b = (const float*)d_in[2];
    const float* W1   = (const float*)d_in[3];
    const float* b1   = (const float*)d_in[4];
    const float* W2   = (const float*)d_in[5];
    const float* b2   = (const float*)d_in[6];
    float* z = (float*)d_out;

    uint16_t* At  = (uint16_t*)d_ws;                 // 2 MB
    uint16_t* Bt  = At + 8192 * 128;                 // 2 MB
    uint16_t* W2f = Bt + 8192 * 128;                 // 256 KB
    uint16_t* W1f = W2f + 128 * 1024;                // 16 KB

    prep_w1<<<32, 256, 0, stream>>>(W1, W1f);
    ln_proj<<<2560, 256, 0, stream>>>(m_in, ln_w, ln_b, W1f, b1, W2, At, Bt, W2f);
    fused_opm<<<2048, 512, 64 * 1024, stream>>>(At, Bt, W2f, b2, z);
}

// Round 21
// 63.341 us; speedup vs baseline: 1.0174x; 1.0068x over previous
//
#include <hip/hip_runtime.h>
#include <stdint.h>

typedef __attribute__((ext_vector_type(8))) short  short8;
typedef __attribute__((ext_vector_type(4))) float  f32x4;

static __device__ __forceinline__ uint32_t f2bf(float x) {
    union { float f; uint32_t u; } v; v.f = x;
    return (v.u + 0x7FFFu + ((v.u >> 16) & 1u)) >> 16;
}

// Fragment-order layout for a 16x32 bf16 MFMA operand tile:
//   frag[(tile*NKS + ks)*512 + lane*8 + e]  where lane = row16 + 16*kh, k = ks*32 + kh*8 + e

// ---------------- kernel 1: LayerNorm + proj via MFMA -> At/Bt fragment order
// Blocks [0,2048): LN+proj (W1 fragments built in-register from raw fp32 W1).
// Blocks [2048,2560): W2f permute (consumed by NEXT kernel).
// At carries proj/128 (OPM scale folded in); Bt carries raw proj.
__global__ __launch_bounds__(256) void ln_proj(
    const float* __restrict__ mI, const float* __restrict__ lnw,
    const float* __restrict__ lnb, const float* __restrict__ W1,
    const float* __restrict__ b1, const float* __restrict__ W2,
    uint16_t* __restrict__ At, uint16_t* __restrict__ Bt,
    uint16_t* __restrict__ W2f)
{
    const int t = threadIdx.x;
    const int bid = blockIdx.x;
    if (bid >= 2048) {                        // ---- W2f prep branch ----
        int idx = (bid - 2048) * 256 + t;     // 0..131071, source-linear
        int f   = idx >> 10;
        int src = idx & 1023;                 // = c*32 + d
        int c = src >> 5, d = src & 31;
        int kd = d * 32 + c;
        int ftile = f >> 4, l16 = f & 15;
        int ks = kd >> 5, kh = (kd >> 3) & 3, e = kd & 7;
        W2f[(size_t)(ftile * 32 + ks) * 512 + (l16 + 16 * kh) * 8 + e] =
            (uint16_t)f2bf(W2[idx]);
        return;
    }

    __shared__ __align__(16) uint16_t mns[256 * 8];   // 4 KB, granule-swizzled
    const int i0 = (bid * 16) & 255;
    const int r  = bid >> 4;
    const int w = t >> 6, l = t & 63;
    const int l16 = l & 15, lh = l >> 4;

    // ---- build W1 fragments in-register (bitwise same as old prep_w1 output):
    // thread needs W1[f*128 + ks*32 + lh*8 + e], f = w*16+l16, e=0..7 — contiguous.
    short8 bw[4];
    {
        const float* W1r = W1 + (size_t)(w * 16 + l16) * 128 + lh * 8;
        #pragma unroll
        for (int ks = 0; ks < 4; ++ks) {
            float4 a0 = *(const float4*)(W1r + ks * 32);
            float4 a1 = *(const float4*)(W1r + ks * 32 + 4);
            union { uint16_t u16[8]; short8 v; } pk;
            pk.u16[0] = (uint16_t)f2bf(a0.x);
            pk.u16[1] = (uint16_t)f2bf(a0.y);
            pk.u16[2] = (uint16_t)f2bf(a0.z);
            pk.u16[3] = (uint16_t)f2bf(a0.w);
            pk.u16[4] = (uint16_t)f2bf(a1.x);
            pk.u16[5] = (uint16_t)f2bf(a1.y);
            pk.u16[6] = (uint16_t)f2bf(a1.z);
            pk.u16[7] = (uint16_t)f2bf(a1.w);
            bw[ks] = pk.v;
        }
    }

    {
        int row = t >> 4, cb = t & 15;
        const float* rp = mI + ((size_t)bid * 16 + row) * 128 + cb * 8;
        float4 v0 = *(const float4*)(rp);
        float4 v1 = *(const float4*)(rp + 4);
        float s  = v0.x + v0.y + v0.z + v0.w + v1.x + v1.y + v1.z + v1.w;
        float ss = v0.x*v0.x + v0.y*v0.y + v0.z*v0.z + v0.w*v0.w
                 + v1.x*v1.x + v1.y*v1.y + v1.z*v1.z + v1.w*v1.w;
        #pragma unroll
        for (int off = 8; off > 0; off >>= 1) {
            s  += __shfl_xor(s, off);
            ss += __shfl_xor(ss, off);
        }
        float mean = s * (1.0f / 128.0f);
        float var  = ss * (1.0f / 128.0f) - mean * mean;
        float rstd = rsqrtf(var + 1e-5f);
        float4 wa = *(const float4*)(lnw + cb * 8);
        float4 wb = *(const float4*)(lnw + cb * 8 + 4);
        float4 ba = *(const float4*)(lnb + cb * 8);
        float4 bb = *(const float4*)(lnb + cb * 8 + 4);
        uint16_t y[8];
        y[0] = (uint16_t)f2bf((v0.x - mean) * rstd * wa.x + ba.x);
        y[1] = (uint16_t)f2bf((v0.y - mean) * rstd * wa.y + ba.y);
        y[2] = (uint16_t)f2bf((v0.z - mean) * rstd * wa.z + ba.z);
        y[3] = (uint16_t)f2bf((v0.w - mean) * rstd * wa.w + ba.w);
        y[4] = (uint16_t)f2bf((v1.x - mean) * rstd * wb.x + bb.x);
        y[5] = (uint16_t)f2bf((v1.y - mean) * rstd * wb.y + bb.y);
        y[6] = (uint16_t)f2bf((v1.z - mean) * rstd * wb.z + bb.z);
        y[7] = (uint16_t)f2bf((v1.w - mean) * rstd * wb.w + bb.w);
        int g = cb * 16 + (row ^ (cb & 7));           // swizzled granule
        *(uint2*)&mns[g * 8]     = *(uint2*)&y[0];
        *(uint2*)&mns[g * 8 + 4] = *(uint2*)&y[4];
    }
    __syncthreads();

    f32x4 acc = (f32x4)(0.0f);
    #pragma unroll
    for (int ks = 0; ks < 4; ++ks) {
        int cb = ks * 4 + lh;
        int g  = cb * 16 + (l16 ^ (cb & 7));
        short8 a = *(const short8*)&mns[g * 8];
        acc = __builtin_amdgcn_mfma_f32_16x16x32_bf16(a, bw[ks], acc, 0, 0, 0);
    }
    float b1v = b1[w * 16 + l16];
    uint16_t* dst = (w < 2) ? At : Bt;
    const float scale = (w < 2) ? (1.0f / 128.0f) : 1.0f;   // fold OPM /128 into At
    const int cch = w & 1;
    const int base2 = (r >> 5) * 512 + (l16 + 16 * ((r >> 3) & 3)) * 8 + (r & 7);
    #pragma unroll
    for (int v = 0; v < 4; ++v) {
        int i = i0 + lh * 4 + v;
        int mtile = i * 2 + cch;
        dst[(size_t)mtile * 2048 + base2] = (uint16_t)f2bf((acc[v] + b1v) * scale);
    }
}

// ---------------- kernel 2: fused OPM GEMM + MFMA W2 epilogue (256x128 tile)
// 1-D grid 2048, XCD-bijective swizzle: lg = (id&7)*256 + id>>3; bx = lg&63, by = lg>>6.
// 512 thr, 8 waves. Main: C[256ic][128jd], wave (wm,wn) does 64x64.
// B-panel (32 KB) staged via async global_load_lds width-16 (no VGPR round trip);
// ks=0 A-frags preloaded pre-barrier (latency overlaps B-DMA). Out LDS region
// reuses the B region after a barrier. Out in FRAGMENT ORDER, ks-XOR swizzled.
// Epi: wave w = f-tile w, 2 p-tiles, 32 ks; W-prefetch depth 8, o-frag depth 2.
extern __shared__ uint16_t outl[];
__global__ __launch_bounds__(512, 4) void fused_opm(
    const uint16_t* __restrict__ At, const uint16_t* __restrict__ Bt,
    const uint16_t* __restrict__ W2f, const float* __restrict__ b2,
    float* __restrict__ z)
{
    const int t = threadIdx.x;
    const int w = t >> 6, l = t & 63;
    const int l16 = l & 15, lh = l >> 4;
    const int id = blockIdx.x;
    const int lg = ((id & 7) << 8) | (id >> 3);   // XCD-contiguous logical tile
    const int bx = lg & 63, by = lg >> 6;
    const int wm = w >> 1, wn = w & 1;

    // ---- stage B panel (32 KB) into LDS[0,32K) via global_load_lds (async) ----
    {
        const uint16_t* Bp = Bt + (size_t)bx * 16384 + (size_t)t * 8;
        uint16_t* dstbase = outl + (size_t)(t & 448) * 8;   // (w*64)*8 elems
        #pragma unroll
        for (int q = 0; q < 4; ++q) {
            __builtin_amdgcn_global_load_lds(
                (const __attribute__((address_space(1))) void*)(Bp + (size_t)q * 4096),
                (__attribute__((address_space(3))) void*)(dstbase + (size_t)q * 4096),
                16, 0, 0);
        }
    }

    // ---- preload ks=0 A-frags NOW (L2 latency overlaps the B-stage DMA) ----
    const uint16_t* Abase = At + (size_t)(by * 16 + wm * 4) * 4 * 512 + l * 8;
    short8 af0[4];
    #pragma unroll
    for (int mt = 0; mt < 4; ++mt)
        af0[mt] = *(const short8*)(Abase + (size_t)(mt * 4) * 512);

    __syncthreads();

    // ---- main GEMM: A-frags from global (1KB/wave), B-frags from LDS ----
    f32x4 acc[4][4];
    #pragma unroll
    for (int a = 0; a < 4; ++a)
        #pragma unroll
        for (int b = 0; b < 4; ++b) acc[a][b] = (f32x4)(0.0f);

    const char* Blds = (const char*)outl + (size_t)wn * 16384 + (size_t)l * 16;
    __builtin_amdgcn_s_setprio(1);
    #pragma unroll
    for (int ks = 0; ks < 4; ++ks) {
        short8 af[4], bf[4];
        #pragma unroll
        for (int mt = 0; mt < 4; ++mt)
            af[mt] = (ks == 0) ? af0[mt]
                   : *(const short8*)(Abase + (size_t)(mt * 4 + ks) * 512);
        #pragma unroll
        for (int nt = 0; nt < 4; ++nt)
            bf[nt] = *(const short8*)(Blds + (size_t)(nt * 4 + ks) * 1024);
        #pragma unroll
        for (int mt = 0; mt < 4; ++mt)
            #pragma unroll
            for (int nt = 0; nt < 4; ++nt)
                acc[mt][nt] = __builtin_amdgcn_mfma_f32_16x16x32_bf16(
                    af[mt], bf[nt], acc[mt][nt], 0, 0, 0);
    }
    __builtin_amdgcn_s_setprio(0);
    __syncthreads();    // all B reads done before Out overwrites the region

    // ---- issue first 8 epilogue W-frag loads NOW (latency hides under C-write) ----
    const uint16_t* Wt = W2f + (size_t)w * 32 * 512 + l * 8;
    short8 wbuf[8];
    #pragma unroll
    for (int q = 0; q < 8; ++q)
        wbuf[q] = *(const short8*)(Wt + (size_t)q * 512);

    // ---- C (pre-scaled by 1/128 via At) -> bf16 -> Out LDS frag-order, ks-XOR swz ----
    #pragma unroll
    for (int mt = 0; mt < 4; ++mt) {
        const int kh = (mt & 1) * 2 + (lh >> 1);
        const int e0 = (lh & 1) * 4;
        #pragma unroll
        for (int nt = 0; nt < 4; ++nt) {
            int p  = wm * 8 + (mt >> 1) * 4 + wn * 2 + (nt >> 1);
            int ks = (nt & 1) * 16 + l16;
            int ptw = p >> 4, l16t = p & 15;
            f32x4 v = acc[mt][nt];
            uint2 pk;
            pk.x = f2bf(v[0]) | (f2bf(v[1]) << 16);
            pk.y = f2bf(v[2]) | (f2bf(v[3]) << 16);
            uint32_t byte = (uint32_t)(ptw * 32 + ks) * 1024u
                          + (uint32_t)(l16t + 16 * kh) * 16u + (uint32_t)e0 * 2u;
            byte ^= (uint32_t)(ks & 7) << 4;
            *(uint2*)((char*)outl + byte) = pk;
        }
    }
    __syncthreads();

    // ---- epilogue: wave w = f-tile w; 2 p-tiles; 32 ks ----
    f32x4 zacc[2][2];
    #pragma unroll
    for (int a = 0; a < 2; ++a) { zacc[a][0] = (f32x4)(0.0f); zacc[a][1] = (f32x4)(0.0f); }

    const char* outb = (const char*)outl;
    #define OB0(ksv) ((((uint32_t)(ksv) * 1024u + (uint32_t)l * 16u)) ^ ((uint32_t)((ksv) & 7) << 4))
    #define OB1(ksv) ((((uint32_t)(32 + (ksv)) * 1024u + (uint32_t)l * 16u)) ^ ((uint32_t)((ksv) & 7) << 4))

    short8 o0c = *(const short8*)(outb + OB0(0));
    short8 o1c = *(const short8*)(outb + OB1(0));
    __builtin_amdgcn_s_setprio(1);
    #pragma unroll
    for (int ks = 0; ks < 32; ++ks) {
        short8 cw = wbuf[ks & 7];
        if (ks < 24) wbuf[ks & 7] = *(const short8*)(Wt + (size_t)(ks + 8) * 512);
        short8 o0 = o0c, o1 = o1c;
        if (ks < 31) {
            o0c = *(const short8*)(outb + OB0(ks + 1));
            o1c = *(const short8*)(outb + OB1(ks + 1));
        }
        zacc[0][ks & 1] = __builtin_amdgcn_mfma_f32_16x16x32_bf16(cw, o0, zacc[0][ks & 1], 0, 0, 0);
        zacc[1][ks & 1] = __builtin_amdgcn_mfma_f32_16x16x32_bf16(cw, o1, zacc[1][ks & 1], 0, 0, 0);
    }
    __builtin_amdgcn_s_setprio(0);
    #undef OB0
    #undef OB1

    // ---- write z: lane p = pt*16+l16, rows f0 = w*16+lh*4 ----
    const int f0 = w * 16 + lh * 4;
    const float4 bv = *(const float4*)(b2 + f0);
    #pragma unroll
    for (int pt = 0; pt < 2; ++pt) {
        int p  = pt * 16 + l16;
        int zi = by * 8 + (p >> 2);
        int zj = bx * 4 + (p & 3);
        float* zrow = z + ((size_t)zi * 256 + zj) * 128;
        float4 zr;
        zr.x = zacc[pt][0][0] + zacc[pt][1][0] + bv.x;
        zr.y = zacc[pt][0][1] + zacc[pt][1][1] + bv.y;
        zr.z = zacc[pt][0][2] + zacc[pt][1][2] + bv.z;
        zr.w = zacc[pt][0][3] + zacc[pt][1][3] + bv.w;
        *(float4*)(zrow + f0) = zr;
    }
}

extern "C" void kernel_launch(void* const* d_in, const int* in_sizes, int n_in,
                              void* d_out, int out_size, void* d_ws, size_t ws_size,
                              hipStream_t stream) {
    const float* m_in = (const float*)d_in[0];
    const float* ln_w = (const float*)d_in[1];
    const float* ln_b = (const float*)d_in[2];
    const float* W1   = (const float*)d_in[3];
    const float* b1   = (const float*)d_in[4];
    const float* W2   = (const float*)d_in[5];
    const float* b2   = (const float*)d_in[6];
    float* z = (float*)d_out;

    uint16_t* At  = (uint16_t*)d_ws;                 // 2 MB
    uint16_t* Bt  = At + 8192 * 128;                 // 2 MB
    uint16_t* W2f = Bt + 8192 * 128;                 // 256 KB

    ln_proj<<<2560, 256, 0, stream>>>(m_in, ln_w, ln_b, W1, b1, W2, At, Bt, W2f);
    fused_opm<<<2048, 512, 64 * 1024, stream>>>(At, Bt, W2f, b2, z);
}

// Round 22
// 61.716 us; speedup vs baseline: 1.0442x; 1.0263x over previous
//
#include <hip/hip_runtime.h>
#include <stdint.h>

typedef __attribute__((ext_vector_type(8))) short  short8;
typedef __attribute__((ext_vector_type(4))) float  f32x4;

static __device__ __forceinline__ uint32_t f2bf(float x) {
    union { float f; uint32_t u; } v; v.f = x;
    return (v.u + 0x7FFFu + ((v.u >> 16) & 1u)) >> 16;
}

// Fragment-order layout for a 16x32 bf16 MFMA operand tile:
//   frag[(tile*NKS + ks)*512 + lane*8 + e]  where lane = row16 + 16*kh, k = ks*32 + kh*8 + e

// ---------------- kernel 1: LayerNorm + proj via MFMA -> At/Bt fragment order
// Blocks [0,2048): LN+proj; block = 2 i x 8 r (16 rows) so each thread's 4 acc
// values are 4 CONSECUTIVE r at fixed (i,f) -> one 8B store (was 4x2B scattered).
// Blocks [2048,2560): W2f permute (consumed by NEXT kernel).
// At carries proj/128 (OPM scale folded in); Bt carries raw proj.
__global__ __launch_bounds__(256) void ln_proj(
    const float* __restrict__ mI, const float* __restrict__ lnw,
    const float* __restrict__ lnb, const float* __restrict__ W1,
    const float* __restrict__ b1, const float* __restrict__ W2,
    uint16_t* __restrict__ At, uint16_t* __restrict__ Bt,
    uint16_t* __restrict__ W2f)
{
    const int t = threadIdx.x;
    const int bid = blockIdx.x;
    if (bid >= 2048) {                        // ---- W2f prep branch ----
        int idx = (bid - 2048) * 256 + t;     // 0..131071, source-linear
        int f   = idx >> 10;
        int src = idx & 1023;                 // = c*32 + d
        int c = src >> 5, d = src & 31;
        int kd = d * 32 + c;
        int ftile = f >> 4, l16 = f & 15;
        int ks = kd >> 5, kh = (kd >> 3) & 3, e = kd & 7;
        W2f[(size_t)(ftile * 32 + ks) * 512 + (l16 + 16 * kh) * 8 + e] =
            (uint16_t)f2bf(W2[idx]);
        return;
    }

    __shared__ __align__(16) uint16_t mns[256 * 8];   // 4 KB, granule-swizzled
    const int ic = bid & 127, rc = bid >> 7;  // i0 = ic*2 (2 i), r0 = rc*8 (8 r)
    const int i0 = ic * 2;
    const int w = t >> 6, l = t & 63;
    const int l16 = l & 15, lh = l >> 4;

    // ---- W1 fragments in-register: thread needs W1[f*128 + ks*32 + lh*8 + e] ----
    short8 bw[4];
    {
        const float* W1r = W1 + (size_t)(w * 16 + l16) * 128 + lh * 8;
        #pragma unroll
        for (int ks = 0; ks < 4; ++ks) {
            float4 a0 = *(const float4*)(W1r + ks * 32);
            float4 a1 = *(const float4*)(W1r + ks * 32 + 4);
            union { uint16_t u16[8]; short8 v; } pk;
            pk.u16[0] = (uint16_t)f2bf(a0.x);
            pk.u16[1] = (uint16_t)f2bf(a0.y);
            pk.u16[2] = (uint16_t)f2bf(a0.z);
            pk.u16[3] = (uint16_t)f2bf(a0.w);
            pk.u16[4] = (uint16_t)f2bf(a1.x);
            pk.u16[5] = (uint16_t)f2bf(a1.y);
            pk.u16[6] = (uint16_t)f2bf(a1.z);
            pk.u16[7] = (uint16_t)f2bf(a1.w);
            bw[ks] = pk.v;
        }
    }

    {   // ---- LN: row = t>>4 maps to (i_l = row>>3, r_l = row&7) ----
        int row = t >> 4, cb = t & 15;
        int rid = (rc * 8 + (row & 7)) * 256 + i0 + (row >> 3);
        const float* rp = mI + (size_t)rid * 128 + cb * 8;
        float4 v0 = *(const float4*)(rp);
        float4 v1 = *(const float4*)(rp + 4);
        float s  = v0.x + v0.y + v0.z + v0.w + v1.x + v1.y + v1.z + v1.w;
        float ss = v0.x*v0.x + v0.y*v0.y + v0.z*v0.z + v0.w*v0.w
                 + v1.x*v1.x + v1.y*v1.y + v1.z*v1.z + v1.w*v1.w;
        #pragma unroll
        for (int off = 8; off > 0; off >>= 1) {
            s  += __shfl_xor(s, off);
            ss += __shfl_xor(ss, off);
        }
        float mean = s * (1.0f / 128.0f);
        float var  = ss * (1.0f / 128.0f) - mean * mean;
        float rstd = rsqrtf(var + 1e-5f);
        float4 wa = *(const float4*)(lnw + cb * 8);
        float4 wb = *(const float4*)(lnw + cb * 8 + 4);
        float4 ba = *(const float4*)(lnb + cb * 8);
        float4 bb = *(const float4*)(lnb + cb * 8 + 4);
        uint16_t y[8];
        y[0] = (uint16_t)f2bf((v0.x - mean) * rstd * wa.x + ba.x);
        y[1] = (uint16_t)f2bf((v0.y - mean) * rstd * wa.y + ba.y);
        y[2] = (uint16_t)f2bf((v0.z - mean) * rstd * wa.z + ba.z);
        y[3] = (uint16_t)f2bf((v0.w - mean) * rstd * wa.w + ba.w);
        y[4] = (uint16_t)f2bf((v1.x - mean) * rstd * wb.x + bb.x);
        y[5] = (uint16_t)f2bf((v1.y - mean) * rstd * wb.y + bb.y);
        y[6] = (uint16_t)f2bf((v1.z - mean) * rstd * wb.z + bb.z);
        y[7] = (uint16_t)f2bf((v1.w - mean) * rstd * wb.w + bb.w);
        int g = cb * 16 + (row ^ (cb & 7));           // swizzled granule
        *(uint2*)&mns[g * 8]     = *(uint2*)&y[0];
        *(uint2*)&mns[g * 8 + 4] = *(uint2*)&y[4];
    }
    __syncthreads();

    f32x4 acc = (f32x4)(0.0f);
    #pragma unroll
    for (int ks = 0; ks < 4; ++ks) {
        int cb = ks * 4 + lh;
        int g  = cb * 16 + (l16 ^ (cb & 7));
        short8 a = *(const short8*)&mns[g * 8];
        acc = __builtin_amdgcn_mfma_f32_16x16x32_bf16(a, bw[ks], acc, 0, 0, 0);
    }
    // acc[v] = proj for row lh*4+v = (i_l = lh>>1, r_l = (lh&1)*4 + v) at f = w*16+l16
    float b1v = b1[w * 16 + l16];
    uint16_t* dst = (w < 2) ? At : Bt;
    const float scale = (w < 2) ? (1.0f / 128.0f) : 1.0f;   // fold OPM /128 into At
    const int cch = w & 1;
    const int mtile = (i0 + (lh >> 1)) * 2 + cch;
    const size_t addr = (size_t)mtile * 2048 + (rc >> 2) * 512
                      + (l16 + 16 * (rc & 3)) * 8 + (lh & 1) * 4;
    uint2 pk;
    pk.x = f2bf((acc[0] + b1v) * scale) | (f2bf((acc[1] + b1v) * scale) << 16);
    pk.y = f2bf((acc[2] + b1v) * scale) | (f2bf((acc[3] + b1v) * scale) << 16);
    *(uint2*)&dst[addr] = pk;
}

// ---------------- kernel 2: fused OPM GEMM + MFMA W2 epilogue (256x128 tile)
// UNCHANGED from R21 (at its measured structural floor).
extern __shared__ uint16_t outl[];
__global__ __launch_bounds__(512, 4) void fused_opm(
    const uint16_t* __restrict__ At, const uint16_t* __restrict__ Bt,
    const uint16_t* __restrict__ W2f, const float* __restrict__ b2,
    float* __restrict__ z)
{
    const int t = threadIdx.x;
    const int w = t >> 6, l = t & 63;
    const int l16 = l & 15, lh = l >> 4;
    const int id = blockIdx.x;
    const int lg = ((id & 7) << 8) | (id >> 3);   // XCD-contiguous logical tile
    const int bx = lg & 63, by = lg >> 6;
    const int wm = w >> 1, wn = w & 1;

    // ---- stage B panel (32 KB) into LDS[0,32K) via global_load_lds (async) ----
    {
        const uint16_t* Bp = Bt + (size_t)bx * 16384 + (size_t)t * 8;
        uint16_t* dstbase = outl + (size_t)(t & 448) * 8;   // (w*64)*8 elems
        #pragma unroll
        for (int q = 0; q < 4; ++q) {
            __builtin_amdgcn_global_load_lds(
                (const __attribute__((address_space(1))) void*)(Bp + (size_t)q * 4096),
                (__attribute__((address_space(3))) void*)(dstbase + (size_t)q * 4096),
                16, 0, 0);
        }
    }

    // ---- preload ks=0 A-frags NOW (L2 latency overlaps the B-stage DMA) ----
    const uint16_t* Abase = At + (size_t)(by * 16 + wm * 4) * 4 * 512 + l * 8;
    short8 af0[4];
    #pragma unroll
    for (int mt = 0; mt < 4; ++mt)
        af0[mt] = *(const short8*)(Abase + (size_t)(mt * 4) * 512);

    __syncthreads();

    // ---- main GEMM: A-frags from global (1KB/wave), B-frags from LDS ----
    f32x4 acc[4][4];
    #pragma unroll
    for (int a = 0; a < 4; ++a)
        #pragma unroll
        for (int b = 0; b < 4; ++b) acc[a][b] = (f32x4)(0.0f);

    const char* Blds = (const char*)outl + (size_t)wn * 16384 + (size_t)l * 16;
    __builtin_amdgcn_s_setprio(1);
    #pragma unroll
    for (int ks = 0; ks < 4; ++ks) {
        short8 af[4], bf[4];
        #pragma unroll
        for (int mt = 0; mt < 4; ++mt)
            af[mt] = (ks == 0) ? af0[mt]
                   : *(const short8*)(Abase + (size_t)(mt * 4 + ks) * 512);
        #pragma unroll
        for (int nt = 0; nt < 4; ++nt)
            bf[nt] = *(const short8*)(Blds + (size_t)(nt * 4 + ks) * 1024);
        #pragma unroll
        for (int mt = 0; mt < 4; ++mt)
            #pragma unroll
            for (int nt = 0; nt < 4; ++nt)
                acc[mt][nt] = __builtin_amdgcn_mfma_f32_16x16x32_bf16(
                    af[mt], bf[nt], acc[mt][nt], 0, 0, 0);
    }
    __builtin_amdgcn_s_setprio(0);
    __syncthreads();    // all B reads done before Out overwrites the region

    // ---- issue first 8 epilogue W-frag loads NOW (latency hides under C-write) ----
    const uint16_t* Wt = W2f + (size_t)w * 32 * 512 + l * 8;
    short8 wbuf[8];
    #pragma unroll
    for (int q = 0; q < 8; ++q)
        wbuf[q] = *(const short8*)(Wt + (size_t)q * 512);

    // ---- C (pre-scaled by 1/128 via At) -> bf16 -> Out LDS frag-order, ks-XOR swz ----
    #pragma unroll
    for (int mt = 0; mt < 4; ++mt) {
        const int kh = (mt & 1) * 2 + (lh >> 1);
        const int e0 = (lh & 1) * 4;
        #pragma unroll
        for (int nt = 0; nt < 4; ++nt) {
            int p  = wm * 8 + (mt >> 1) * 4 + wn * 2 + (nt >> 1);
            int ks = (nt & 1) * 16 + l16;
            int ptw = p >> 4, l16t = p & 15;
            f32x4 v = acc[mt][nt];
            uint2 pk;
            pk.x = f2bf(v[0]) | (f2bf(v[1]) << 16);
            pk.y = f2bf(v[2]) | (f2bf(v[3]) << 16);
            uint32_t byte = (uint32_t)(ptw * 32 + ks) * 1024u
                          + (uint32_t)(l16t + 16 * kh) * 16u + (uint32_t)e0 * 2u;
            byte ^= (uint32_t)(ks & 7) << 4;
            *(uint2*)((char*)outl + byte) = pk;
        }
    }
    __syncthreads();

    // ---- epilogue: wave w = f-tile w; 2 p-tiles; 32 ks ----
    f32x4 zacc[2][2];
    #pragma unroll
    for (int a = 0; a < 2; ++a) { zacc[a][0] = (f32x4)(0.0f); zacc[a][1] = (f32x4)(0.0f); }

    const char* outb = (const char*)outl;
    #define OB0(ksv) ((((uint32_t)(ksv) * 1024u + (uint32_t)l * 16u)) ^ ((uint32_t)((ksv) & 7) << 4))
    #define OB1(ksv) ((((uint32_t)(32 + (ksv)) * 1024u + (uint32_t)l * 16u)) ^ ((uint32_t)((ksv) & 7) << 4))

    short8 o0c = *(const short8*)(outb + OB0(0));
    short8 o1c = *(const short8*)(outb + OB1(0));
    __builtin_amdgcn_s_setprio(1);
    #pragma unroll
    for (int ks = 0; ks < 32; ++ks) {
        short8 cw = wbuf[ks & 7];
        if (ks < 24) wbuf[ks & 7] = *(const short8*)(Wt + (size_t)(ks + 8) * 512);
        short8 o0 = o0c, o1 = o1c;
        if (ks < 31) {
            o0c = *(const short8*)(outb + OB0(ks + 1));
            o1c = *(const short8*)(outb + OB1(ks + 1));
        }
        zacc[0][ks & 1] = __builtin_amdgcn_mfma_f32_16x16x32_bf16(cw, o0, zacc[0][ks & 1], 0, 0, 0);
        zacc[1][ks & 1] = __builtin_amdgcn_mfma_f32_16x16x32_bf16(cw, o1, zacc[1][ks & 1], 0, 0, 0);
    }
    __builtin_amdgcn_s_setprio(0);
    #undef OB0
    #undef OB1

    // ---- write z: lane p = pt*16+l16, rows f0 = w*16+lh*4 ----
    const int f0 = w * 16 + lh * 4;
    const float4 bv = *(const float4*)(b2 + f0);
    #pragma unroll
    for (int pt = 0; pt < 2; ++pt) {
        int p  = pt * 16 + l16;
        int zi = by * 8 + (p >> 2);
        int zj = bx * 4 + (p & 3);
        float* zrow = z + ((size_t)zi * 256 + zj) * 128;
        float4 zr;
        zr.x = zacc[pt][0][0] + zacc[pt][1][0] + bv.x;
        zr.y = zacc[pt][0][1] + zacc[pt][1][1] + bv.y;
        zr.z = zacc[pt][0][2] + zacc[pt][1][2] + bv.z;
        zr.w = zacc[pt][0][3] + zacc[pt][1][3] + bv.w;
        *(float4*)(zrow + f0) = zr;
    }
}

extern "C" void kernel_launch(void* const* d_in, const int* in_sizes, int n_in,
                              void* d_out, int out_size, void* d_ws, size_t ws_size,
                              hipStream_t stream) {
    const float* m_in = (const float*)d_in[0];
    const float* ln_w = (const float*)d_in[1];
    const float* ln_b = (const float*)d_in[2];
    const float* W1   = (const float*)d_in[3];
    const float* b1   = (const float*)d_in[4];
    const float* W2   = (const float*)d_in[5];
    const float* b2   = (const float*)d_in[6];
    float* z = (float*)d_out;

    uint16_t* At  = (uint16_t*)d_ws;                 // 2 MB
    uint16_t* Bt  = At + 8192 * 128;                 // 2 MB
    uint16_t* W2f = Bt + 8192 * 128;                 // 256 KB

    ln_proj<<<2560, 256, 0, stream>>>(m_in, ln_w, ln_b, W1, b1, W2, At, Bt, W2f);
    fused_opm<<<2048, 512, 64 * 1024, stream>>>(At, Bt, W2f, b2, z);
}